// Round 1
// baseline (1674.922 us; speedup 1.0000x reference)
//
#include <hip/hip_runtime.h>

#define D_MODEL 1024
#define N_HEADS 16
#define DK 64
#define LSEQ 512
#define BATCH 4
#define M_ROWS (BATCH * LSEQ)   // 2048

// ---------------------------------------------------------------------------
// GEMM: out[M,N] = X[M,K] @ W[K,N] + bvec[N] (+ res[M,N] if ADD_RES)
// 64x64 tile, BK=16, 256 threads, 4x4 micro-tile per thread.
// M%64==0, N%64==0, K%16==0 assumed (holds: 2048/1024/1024).
// ---------------------------------------------------------------------------
template <bool ADD_RES>
__global__ __launch_bounds__(256) void gemm64(
    const float* __restrict__ X, const float* __restrict__ W,
    const float* __restrict__ bvec, const float* __restrict__ res,
    float* __restrict__ out, int M, int N, int K)
{
    __shared__ float As[16][64];   // [k][m]
    __shared__ float Bs[16][64];   // [k][n]

    const int tid = threadIdx.x;
    const int tx = tid & 15;       // 0..15 -> col group
    const int ty = tid >> 4;       // 0..15 -> row group
    const int rowBase = blockIdx.y * 64;
    const int colBase = blockIdx.x * 64;

    // A-load mapping: each thread loads float4 of one row
    const int a_r = tid >> 2;          // 0..63
    const int a_k = (tid & 3) * 4;     // 0,4,8,12
    // B-load mapping: each thread loads float4 of one k-row
    const int b_k = tid >> 4;          // 0..15
    const int b_c = (tid & 15) * 4;    // 0..60

    const float* Xp = X + (size_t)(rowBase + a_r) * K + a_k;
    const float* Wp = W + (size_t)b_k * N + colBase + b_c;

    float acc[4][4] = {};

    for (int k0 = 0; k0 < K; k0 += 16) {
        float4 av = *(const float4*)(Xp + k0);
        float4 bv = *(const float4*)(Wp + (size_t)k0 * N);
        As[a_k + 0][a_r] = av.x;
        As[a_k + 1][a_r] = av.y;
        As[a_k + 2][a_r] = av.z;
        As[a_k + 3][a_r] = av.w;
        *(float4*)&Bs[b_k][b_c] = bv;
        __syncthreads();

        #pragma unroll
        for (int kk = 0; kk < 16; ++kk) {
            float a0 = As[kk][ty * 4 + 0];
            float a1 = As[kk][ty * 4 + 1];
            float a2 = As[kk][ty * 4 + 2];
            float a3 = As[kk][ty * 4 + 3];
            float b0 = Bs[kk][tx * 4 + 0];
            float b1 = Bs[kk][tx * 4 + 1];
            float b2 = Bs[kk][tx * 4 + 2];
            float b3 = Bs[kk][tx * 4 + 3];
            acc[0][0] += a0 * b0; acc[0][1] += a0 * b1; acc[0][2] += a0 * b2; acc[0][3] += a0 * b3;
            acc[1][0] += a1 * b0; acc[1][1] += a1 * b1; acc[1][2] += a1 * b2; acc[1][3] += a1 * b3;
            acc[2][0] += a2 * b0; acc[2][1] += a2 * b1; acc[2][2] += a2 * b2; acc[2][3] += a2 * b3;
            acc[3][0] += a3 * b0; acc[3][1] += a3 * b1; acc[3][2] += a3 * b2; acc[3][3] += a3 * b3;
        }
        __syncthreads();
    }

    #pragma unroll
    for (int i = 0; i < 4; ++i) {
        int r = rowBase + ty * 4 + i;
        #pragma unroll
        for (int j = 0; j < 4; ++j) {
            int c = colBase + tx * 4 + j;
            float v = acc[i][j] + bvec[c];
            if (ADD_RES) v += res[(size_t)r * N + c];
            out[(size_t)r * N + c] = v;
        }
    }
}

// ---------------------------------------------------------------------------
// Attention: one block per (b,h,lq). 256 threads.
// qh/kh/vh in [B*L, H*64] layout (head slice contiguous 64 floats).
// scores = (q.k)/8 + bias + gbias, softmax over 512 keys, ctx = w @ v.
// ctx written to [B*L, H*64].
// ---------------------------------------------------------------------------
__global__ __launch_bounds__(256) void attn_kernel(
    const float* __restrict__ qh, const float* __restrict__ kh,
    const float* __restrict__ vh, const float* __restrict__ bias,
    const float* __restrict__ gbias, float* __restrict__ ctx)
{
    const int idx = blockIdx.x;        // (b*H + h)*L + lq
    const int lq = idx & (LSEQ - 1);
    const int bh = idx >> 9;           // b*16 + h
    const int h = bh & (N_HEADS - 1);
    const int b = bh >> 4;

    const float* qrow  = qh + ((size_t)(b * LSEQ + lq)) * D_MODEL + h * DK;
    const float* kbase = kh + ((size_t)(b * LSEQ)) * D_MODEL + h * DK;
    const float* vbase = vh + ((size_t)(b * LSEQ)) * D_MODEL + h * DK;
    const float* brow  = bias  + ((size_t)bh * LSEQ + lq) * LSEQ;
    const float* gbrow = gbias + ((size_t)bh * LSEQ + lq) * LSEQ;

    __shared__ float qs[DK];
    __shared__ float sc[LSEQ];
    __shared__ float red[256];

    const int tid = threadIdx.x;
    if (tid < DK) qs[tid] = qrow[tid];
    __syncthreads();

    // scores
    #pragma unroll
    for (int kk = 0; kk < 2; ++kk) {
        int k = tid + kk * 256;
        const float4* kr4 = (const float4*)(kbase + (size_t)k * D_MODEL);
        float acc = 0.f;
        #pragma unroll
        for (int d4 = 0; d4 < 16; ++d4) {
            float4 kv = kr4[d4];
            acc += qs[d4 * 4 + 0] * kv.x + qs[d4 * 4 + 1] * kv.y +
                   qs[d4 * 4 + 2] * kv.z + qs[d4 * 4 + 3] * kv.w;
        }
        sc[k] = acc * 0.125f + brow[k] + gbrow[k];
    }
    __syncthreads();

    // max reduce
    red[tid] = fmaxf(sc[tid], sc[tid + 256]);
    __syncthreads();
    for (int s = 128; s > 0; s >>= 1) {
        if (tid < s) red[tid] = fmaxf(red[tid], red[tid + s]);
        __syncthreads();
    }
    const float mx = red[0];
    __syncthreads();

    // exp + sum reduce
    float e0 = __expf(sc[tid] - mx);
    float e1 = __expf(sc[tid + 256] - mx);
    sc[tid] = e0;
    sc[tid + 256] = e1;
    red[tid] = e0 + e1;
    __syncthreads();
    for (int s = 128; s > 0; s >>= 1) {
        if (tid < s) red[tid] += red[tid + s];
        __syncthreads();
    }
    const float inv = 1.0f / red[0];
    __syncthreads();

    // ctx: thread t -> d = t&63, k-chunk = t>>6 (4 chunks x 128)
    const int d = tid & (DK - 1);
    const int c = tid >> 6;
    float acc = 0.f;
    const int k0 = c * 128;
    for (int k = k0; k < k0 + 128; ++k)
        acc += sc[k] * vbase[(size_t)k * D_MODEL + d];
    red[tid] = acc;
    __syncthreads();
    if (tid < DK) {
        float r = red[tid] + red[tid + 64] + red[tid + 128] + red[tid + 192];
        ctx[((size_t)(b * LSEQ + lq)) * D_MODEL + h * DK + tid] = r * inv;
    }
}

// ---------------------------------------------------------------------------
// In-place per-row LayerNorm over D=1024. One block per row, 256 threads.
// ---------------------------------------------------------------------------
__global__ __launch_bounds__(256) void ln_kernel(
    float* __restrict__ x, const float* __restrict__ g,
    const float* __restrict__ beta)
{
    const int row = blockIdx.x;
    float* xr = x + (size_t)row * D_MODEL;
    const int tid = threadIdx.x;

    float v[4];
    float s = 0.f, sq = 0.f;
    #pragma unroll
    for (int j = 0; j < 4; ++j) {
        v[j] = xr[tid + 256 * j];
        s += v[j];
        sq += v[j] * v[j];
    }
    __shared__ float rs[256], rq[256];
    rs[tid] = s;
    rq[tid] = sq;
    __syncthreads();
    for (int st = 128; st > 0; st >>= 1) {
        if (tid < st) { rs[tid] += rs[tid + st]; rq[tid] += rq[tid + st]; }
        __syncthreads();
    }
    const float mean = rs[0] * (1.0f / D_MODEL);
    const float var = rq[0] * (1.0f / D_MODEL) - mean * mean;
    const float rinv = rsqrtf(var + 1e-6f);
    #pragma unroll
    for (int j = 0; j < 4; ++j) {
        int n = tid + 256 * j;
        xr[n] = (v[j] - mean) * rinv * g[n] + beta[n];
    }
}

// ---------------------------------------------------------------------------
extern "C" void kernel_launch(void* const* d_in, const int* in_sizes, int n_in,
                              void* d_out, int out_size, void* d_ws, size_t ws_size,
                              hipStream_t stream)
{
    const float* q     = (const float*)d_in[0];
    const float* k     = (const float*)d_in[1];
    const float* v     = (const float*)d_in[2];
    const float* bias  = (const float*)d_in[3];
    const float* gbias = (const float*)d_in[4];
    const float* wq    = (const float*)d_in[5];
    const float* bq    = (const float*)d_in[6];
    const float* wk    = (const float*)d_in[7];
    const float* bk    = (const float*)d_in[8];
    const float* wv    = (const float*)d_in[9];
    const float* bv    = (const float*)d_in[10];
    const float* wo    = (const float*)d_in[11];
    const float* bo    = (const float*)d_in[12];
    const float* ln_g  = (const float*)d_in[13];
    const float* ln_b  = (const float*)d_in[14];

    float* ws  = (float*)d_ws;
    const size_t SLAB = (size_t)M_ROWS * D_MODEL;  // 2,097,152 floats = 8 MB
    float* qh  = ws;
    float* kh  = ws + SLAB;
    float* vh  = ws + 2 * SLAB;
    float* ctx = ws + 3 * SLAB;
    float* outp = (float*)d_out;

    dim3 gblk(D_MODEL / 64, M_ROWS / 64);  // (16, 32)

    gemm64<false><<<gblk, 256, 0, stream>>>(q, wq, bq, nullptr, qh, M_ROWS, D_MODEL, D_MODEL);
    gemm64<false><<<gblk, 256, 0, stream>>>(k, wk, bk, nullptr, kh, M_ROWS, D_MODEL, D_MODEL);
    gemm64<false><<<gblk, 256, 0, stream>>>(v, wv, bv, nullptr, vh, M_ROWS, D_MODEL, D_MODEL);

    attn_kernel<<<BATCH * N_HEADS * LSEQ, 256, 0, stream>>>(qh, kh, vh, bias, gbias, ctx);

    gemm64<true><<<gblk, 256, 0, stream>>>(ctx, wo, bo, q, outp, M_ROWS, D_MODEL, D_MODEL);

    ln_kernel<<<M_ROWS, 256, 0, stream>>>(outp, ln_g, ln_b);
}

// Round 2
// 589.475 us; speedup vs baseline: 2.8414x; 2.8414x over previous
//
#include <hip/hip_runtime.h>

#define D_MODEL 1024
#define N_HEADS 16
#define DK 64
#define LSEQ 512
#define BATCH 4
#define M_ROWS (BATCH * LSEQ)   // 2048

// ---------------------------------------------------------------------------
// GEMM: out[M,N] = X[M,K] @ W[K,N] + bvec[N] (+ res[M,N] if ADD_RES)
// 64x64 tile, BK=16, 256 threads, 4x4 micro-tile per thread.
// ---------------------------------------------------------------------------
template <bool ADD_RES>
__global__ __launch_bounds__(256) void gemm64(
    const float* __restrict__ X, const float* __restrict__ W,
    const float* __restrict__ bvec, const float* __restrict__ res,
    float* __restrict__ out, int M, int N, int K)
{
    __shared__ float As[16][64];   // [k][m]
    __shared__ float Bs[16][64];   // [k][n]

    const int tid = threadIdx.x;
    const int tx = tid & 15;
    const int ty = tid >> 4;
    const int rowBase = blockIdx.y * 64;
    const int colBase = blockIdx.x * 64;

    const int a_r = tid >> 2;
    const int a_k = (tid & 3) * 4;
    const int b_k = tid >> 4;
    const int b_c = (tid & 15) * 4;

    const float* Xp = X + (size_t)(rowBase + a_r) * K + a_k;
    const float* Wp = W + (size_t)b_k * N + colBase + b_c;

    float acc[4][4] = {};

    for (int k0 = 0; k0 < K; k0 += 16) {
        float4 av = *(const float4*)(Xp + k0);
        float4 bv = *(const float4*)(Wp + (size_t)k0 * N);
        As[a_k + 0][a_r] = av.x;
        As[a_k + 1][a_r] = av.y;
        As[a_k + 2][a_r] = av.z;
        As[a_k + 3][a_r] = av.w;
        *(float4*)&Bs[b_k][b_c] = bv;
        __syncthreads();

        #pragma unroll
        for (int kk = 0; kk < 16; ++kk) {
            float a0 = As[kk][ty * 4 + 0];
            float a1 = As[kk][ty * 4 + 1];
            float a2 = As[kk][ty * 4 + 2];
            float a3 = As[kk][ty * 4 + 3];
            float b0 = Bs[kk][tx * 4 + 0];
            float b1 = Bs[kk][tx * 4 + 1];
            float b2 = Bs[kk][tx * 4 + 2];
            float b3 = Bs[kk][tx * 4 + 3];
            acc[0][0] += a0 * b0; acc[0][1] += a0 * b1; acc[0][2] += a0 * b2; acc[0][3] += a0 * b3;
            acc[1][0] += a1 * b0; acc[1][1] += a1 * b1; acc[1][2] += a1 * b2; acc[1][3] += a1 * b3;
            acc[2][0] += a2 * b0; acc[2][1] += a2 * b1; acc[2][2] += a2 * b2; acc[2][3] += a2 * b3;
            acc[3][0] += a3 * b0; acc[3][1] += a3 * b1; acc[3][2] += a3 * b2; acc[3][3] += a3 * b3;
        }
        __syncthreads();
    }

    #pragma unroll
    for (int i = 0; i < 4; ++i) {
        int r = rowBase + ty * 4 + i;
        #pragma unroll
        for (int j = 0; j < 4; ++j) {
            int c = colBase + tx * 4 + j;
            float v = acc[i][j] + bvec[c];
            if (ADD_RES) v += res[(size_t)r * N + c];
            out[(size_t)r * N + c] = v;
        }
    }
}

// ---------------------------------------------------------------------------
// Tiled attention: one block = 16 query rows x one (b,h). 256 threads.
// K staged transposed [d][k] (stride 66), V row-major [k][d] (stride 68),
// scores in LDS fp32 [16][516]. Softmax 1/sum folded into PV epilogue.
// Grid: (LSEQ/16, BATCH*N_HEADS) = (32, 64).
// ---------------------------------------------------------------------------
__global__ __launch_bounds__(256) void attn_tiled(
    const float* __restrict__ qh, const float* __restrict__ kmat,
    const float* __restrict__ vmat, const float* __restrict__ bias,
    const float* __restrict__ gbias, float* __restrict__ ctx)
{
    __shared__ float Qs[16][64];        // 4 KB
    __shared__ float S[16][516];        // 32.25 KB
    __shared__ float KVu[64 * 68];      // 17 KB (union: Kt stride 66 / Vs stride 68)
    __shared__ float red[16][17];
    __shared__ float rowmax[16];
    __shared__ float rowinv[16];

    const int tid = threadIdx.x;
    const int bh = blockIdx.y;          // b*16 + h
    const int h = bh & (N_HEADS - 1);
    const int b = bh >> 4;
    const int q0 = blockIdx.x * 16;

    const float* qbase = qh  + ((size_t)(b * LSEQ + q0)) * D_MODEL + h * DK;
    const float* kbase = kmat + ((size_t)(b * LSEQ)) * D_MODEL + h * DK;
    const float* vbase = vmat + ((size_t)(b * LSEQ)) * D_MODEL + h * DK;
    const size_t biasRow = ((size_t)bh * LSEQ + q0) * LSEQ;

    // ---- load Q tile (16x64) ----
    {
        int qr = tid >> 4, qd = (tid & 15) * 4;
        *(float4*)&Qs[qr][qd] = *(const float4*)(qbase + (size_t)qr * D_MODEL + qd);
    }

    // ---- score phase: S[q][k] = (Q.K)/8 + bias + gbias ----
    const int s_qg = tid >> 5;      // 0..7 -> q = 2*s_qg
    const int s_kg = tid & 31;      // 0..31 -> k = 2*s_kg (within 64-tile)
    const int sq_ = 2 * s_qg;

    for (int it = 0; it < 8; ++it) {
        const int k0 = it * 64;
        // stage K-tile transposed: Kt[d][kk], stride 66
        #pragma unroll
        for (int j = 0; j < 4; ++j) {
            int kk = (tid >> 4) + 16 * j;
            int dd = (tid & 15) * 4;
            float4 t = *(const float4*)(kbase + (size_t)(k0 + kk) * D_MODEL + dd);
            KVu[(dd + 0) * 66 + kk] = t.x;
            KVu[(dd + 1) * 66 + kk] = t.y;
            KVu[(dd + 2) * 66 + kk] = t.z;
            KVu[(dd + 3) * 66 + kk] = t.w;
        }
        __syncthreads();

        float acc00 = 0.f, acc01 = 0.f, acc10 = 0.f, acc11 = 0.f;
        #pragma unroll
        for (int d4 = 0; d4 < 64; d4 += 4) {
            float4 a0 = *(float4*)&Qs[sq_][d4];
            float4 a1 = *(float4*)&Qs[sq_ + 1][d4];
            float2 k0v = *(float2*)&KVu[(d4 + 0) * 66 + 2 * s_kg];
            float2 k1v = *(float2*)&KVu[(d4 + 1) * 66 + 2 * s_kg];
            float2 k2v = *(float2*)&KVu[(d4 + 2) * 66 + 2 * s_kg];
            float2 k3v = *(float2*)&KVu[(d4 + 3) * 66 + 2 * s_kg];
            acc00 += a0.x * k0v.x + a0.y * k1v.x + a0.z * k2v.x + a0.w * k3v.x;
            acc01 += a0.x * k0v.y + a0.y * k1v.y + a0.z * k2v.y + a0.w * k3v.y;
            acc10 += a1.x * k0v.x + a1.y * k1v.x + a1.z * k2v.x + a1.w * k3v.x;
            acc11 += a1.x * k0v.y + a1.y * k1v.y + a1.z * k2v.y + a1.w * k3v.y;
        }

        const int kglob = k0 + 2 * s_kg;
        float2 b0 = *(const float2*)(bias  + biasRow + (size_t)sq_ * LSEQ + kglob);
        float2 g0 = *(const float2*)(gbias + biasRow + (size_t)sq_ * LSEQ + kglob);
        float2 b1 = *(const float2*)(bias  + biasRow + (size_t)(sq_ + 1) * LSEQ + kglob);
        float2 g1 = *(const float2*)(gbias + biasRow + (size_t)(sq_ + 1) * LSEQ + kglob);
        float2 o0 = make_float2(acc00 * 0.125f + b0.x + g0.x, acc01 * 0.125f + b0.y + g0.y);
        float2 o1 = make_float2(acc10 * 0.125f + b1.x + g1.x, acc11 * 0.125f + b1.y + g1.y);
        *(float2*)&S[sq_][kglob] = o0;
        *(float2*)&S[sq_ + 1][kglob] = o1;
        __syncthreads();
    }

    // ---- softmax (exp stored in S; 1/sum deferred to epilogue) ----
    {
        const int sq = tid >> 4, sc = tid & 15;
        float m = -1e30f;
        #pragma unroll
        for (int i = 0; i < 32; ++i) m = fmaxf(m, S[sq][sc + 16 * i]);
        red[sq][sc] = m;
        __syncthreads();
        if (tid < 16) {
            float mm = red[tid][0];
            #pragma unroll
            for (int c = 1; c < 16; ++c) mm = fmaxf(mm, red[tid][c]);
            rowmax[tid] = mm;
        }
        __syncthreads();
        const float mx = rowmax[sq];
        float ssum = 0.f;
        #pragma unroll
        for (int i = 0; i < 32; ++i) {
            float e = __expf(S[sq][sc + 16 * i] - mx);
            S[sq][sc + 16 * i] = e;
            ssum += e;
        }
        red[sq][sc] = ssum;
        __syncthreads();
        if (tid < 16) {
            float t = 0.f;
            #pragma unroll
            for (int c = 0; c < 16; ++c) t += red[tid][c];
            rowinv[tid] = 1.0f / t;
        }
        __syncthreads();
    }

    // ---- PV phase: O[q][d] = sum_k P[q][k] V[k][d] ----
    const int p_qg = (tid >> 4) & 7;    // q = 2*p_qg
    const int p_dg = tid & 15;          // d = 4*p_dg
    const int p_kh = tid >> 7;          // k-half within tile
    const int pq = 2 * p_qg;
    const int pd = 4 * p_dg;
    float o0x = 0.f, o0y = 0.f, o0z = 0.f, o0w = 0.f;
    float o1x = 0.f, o1y = 0.f, o1z = 0.f, o1w = 0.f;

    for (int it = 0; it < 8; ++it) {
        const int k0 = it * 64;
        // stage V-tile row-major: Vs[kk][d], stride 68
        #pragma unroll
        for (int j = 0; j < 4; ++j) {
            int kk = (tid >> 4) + 16 * j;
            int dd = (tid & 15) * 4;
            *(float4*)&KVu[kk * 68 + dd] =
                *(const float4*)(vbase + (size_t)(k0 + kk) * D_MODEL + dd);
        }
        __syncthreads();

        #pragma unroll
        for (int k4 = 0; k4 < 8; ++k4) {
            const int kl = 32 * p_kh + 4 * k4;
            float4 p0 = *(float4*)&S[pq][k0 + kl];
            float4 p1 = *(float4*)&S[pq + 1][k0 + kl];
            float4 v0 = *(float4*)&KVu[(kl + 0) * 68 + pd];
            float4 v1 = *(float4*)&KVu[(kl + 1) * 68 + pd];
            float4 v2 = *(float4*)&KVu[(kl + 2) * 68 + pd];
            float4 v3 = *(float4*)&KVu[(kl + 3) * 68 + pd];
            o0x += p0.x * v0.x + p0.y * v1.x + p0.z * v2.x + p0.w * v3.x;
            o0y += p0.x * v0.y + p0.y * v1.y + p0.z * v2.y + p0.w * v3.y;
            o0z += p0.x * v0.z + p0.y * v1.z + p0.z * v2.z + p0.w * v3.z;
            o0w += p0.x * v0.w + p0.y * v1.w + p0.z * v2.w + p0.w * v3.w;
            o1x += p1.x * v0.x + p1.y * v1.x + p1.z * v2.x + p1.w * v3.x;
            o1y += p1.x * v0.y + p1.y * v1.y + p1.z * v2.y + p1.w * v3.y;
            o1z += p1.x * v0.z + p1.y * v1.z + p1.z * v2.z + p1.w * v3.z;
            o1w += p1.x * v0.w + p1.y * v1.w + p1.z * v2.w + p1.w * v3.w;
        }
        __syncthreads();
    }

    // ---- reduce k-halves via LDS (reuse KVu), scale by 1/sum, write ctx ----
    if (p_kh == 1) {
        float* dst = &KVu[(size_t)(tid & 127) * 8];
        dst[0] = o0x; dst[1] = o0y; dst[2] = o0z; dst[3] = o0w;
        dst[4] = o1x; dst[5] = o1y; dst[6] = o1z; dst[7] = o1w;
    }
    __syncthreads();
    if (p_kh == 0) {
        const float* src = &KVu[(size_t)tid * 8];
        const float inv0 = rowinv[pq];
        const float inv1 = rowinv[pq + 1];
        float4 w0 = make_float4((o0x + src[0]) * inv0, (o0y + src[1]) * inv0,
                                (o0z + src[2]) * inv0, (o0w + src[3]) * inv0);
        float4 w1 = make_float4((o1x + src[4]) * inv1, (o1y + src[5]) * inv1,
                                (o1z + src[6]) * inv1, (o1w + src[7]) * inv1);
        float* crow0 = ctx + ((size_t)(b * LSEQ + q0 + pq)) * D_MODEL + h * DK + pd;
        float* crow1 = ctx + ((size_t)(b * LSEQ + q0 + pq + 1)) * D_MODEL + h * DK + pd;
        *(float4*)crow0 = w0;
        *(float4*)crow1 = w1;
    }
}

// ---------------------------------------------------------------------------
// In-place per-row LayerNorm over D=1024. One block per row, 256 threads.
// ---------------------------------------------------------------------------
__global__ __launch_bounds__(256) void ln_kernel(
    float* __restrict__ x, const float* __restrict__ g,
    const float* __restrict__ beta)
{
    const int row = blockIdx.x;
    float* xr = x + (size_t)row * D_MODEL;
    const int tid = threadIdx.x;

    float v[4];
    float s = 0.f, sq = 0.f;
    #pragma unroll
    for (int j = 0; j < 4; ++j) {
        v[j] = xr[tid + 256 * j];
        s += v[j];
        sq += v[j] * v[j];
    }
    __shared__ float rs[256], rq[256];
    rs[tid] = s;
    rq[tid] = sq;
    __syncthreads();
    for (int st = 128; st > 0; st >>= 1) {
        if (tid < st) { rs[tid] += rs[tid + st]; rq[tid] += rq[tid + st]; }
        __syncthreads();
    }
    const float mean = rs[0] * (1.0f / D_MODEL);
    const float var = rq[0] * (1.0f / D_MODEL) - mean * mean;
    const float rinv = rsqrtf(var + 1e-6f);
    #pragma unroll
    for (int j = 0; j < 4; ++j) {
        int n = tid + 256 * j;
        xr[n] = (v[j] - mean) * rinv * g[n] + beta[n];
    }
}

// ---------------------------------------------------------------------------
extern "C" void kernel_launch(void* const* d_in, const int* in_sizes, int n_in,
                              void* d_out, int out_size, void* d_ws, size_t ws_size,
                              hipStream_t stream)
{
    const float* q     = (const float*)d_in[0];
    const float* k     = (const float*)d_in[1];
    const float* v     = (const float*)d_in[2];
    const float* bias  = (const float*)d_in[3];
    const float* gbias = (const float*)d_in[4];
    const float* wq    = (const float*)d_in[5];
    const float* bq    = (const float*)d_in[6];
    const float* wk    = (const float*)d_in[7];
    const float* bk    = (const float*)d_in[8];
    const float* wv    = (const float*)d_in[9];
    const float* bv    = (const float*)d_in[10];
    const float* wo    = (const float*)d_in[11];
    const float* bo    = (const float*)d_in[12];
    const float* ln_g  = (const float*)d_in[13];
    const float* ln_b  = (const float*)d_in[14];

    float* ws  = (float*)d_ws;
    const size_t SLAB = (size_t)M_ROWS * D_MODEL;  // 8 MB each
    float* qh  = ws;
    float* kh  = ws + SLAB;
    float* vh  = ws + 2 * SLAB;
    float* ctx = ws + 3 * SLAB;
    float* outp = (float*)d_out;

    dim3 gblk(D_MODEL / 64, M_ROWS / 64);  // (16, 32)

    gemm64<false><<<gblk, 256, 0, stream>>>(q, wq, bq, nullptr, qh, M_ROWS, D_MODEL, D_MODEL);
    gemm64<false><<<gblk, 256, 0, stream>>>(k, wk, bk, nullptr, kh, M_ROWS, D_MODEL, D_MODEL);
    gemm64<false><<<gblk, 256, 0, stream>>>(v, wv, bv, nullptr, vh, M_ROWS, D_MODEL, D_MODEL);

    dim3 ablk(LSEQ / 16, BATCH * N_HEADS);  // (32, 64)
    attn_tiled<<<ablk, 256, 0, stream>>>(qh, kh, vh, bias, gbias, ctx);

    gemm64<true><<<gblk, 256, 0, stream>>>(ctx, wo, bo, q, outp, M_ROWS, D_MODEL, D_MODEL);

    ln_kernel<<<M_ROWS, 256, 0, stream>>>(outp, ln_g, ln_b);
}

// Round 3
// 378.334 us; speedup vs baseline: 4.4271x; 1.5581x over previous
//
#include <hip/hip_runtime.h>

#define D_MODEL 1024
#define N_HEADS 16
#define DK 64
#define LSEQ 512
#define BATCH 4
#define M_ROWS (BATCH * LSEQ)   // 2048

typedef unsigned short ushort_t;
typedef __attribute__((ext_vector_type(8))) short short8;
typedef __attribute__((ext_vector_type(4))) float floatx4;

__device__ __forceinline__ float bf2f(unsigned short u) {
    return __uint_as_float(((unsigned int)u) << 16);
}
__device__ __forceinline__ unsigned short f2bf(float f) {
    unsigned int u = __float_as_uint(f);
    u += 0x7fffu + ((u >> 16) & 1u);   // round-to-nearest-even
    return (unsigned short)(u >> 16);
}

// ---------------------------------------------------------------------------
// cast3: three fp32 arrays -> bf16, 4 elems/thread. grid (n/1024, 3)
// ---------------------------------------------------------------------------
__global__ __launch_bounds__(256) void cast3_kernel(
    const float* __restrict__ a, const float* __restrict__ b,
    const float* __restrict__ c, ushort_t* __restrict__ oa,
    ushort_t* __restrict__ ob, ushort_t* __restrict__ oc, int n)
{
    const float* src = (blockIdx.y == 0) ? a : (blockIdx.y == 1) ? b : c;
    ushort_t* dst = (blockIdx.y == 0) ? oa : (blockIdx.y == 1) ? ob : oc;
    int i = (blockIdx.x * 256 + threadIdx.x) * 4;
    if (i + 3 < n) {
        float4 v = *(const float4*)(src + i);
        ushort4 o = make_ushort4(f2bf(v.x), f2bf(v.y), f2bf(v.z), f2bf(v.w));
        *(ushort4*)(dst + i) = o;
    }
}

// ---------------------------------------------------------------------------
// transpose4: W[k][n] fp32 (1024x1024) -> Wt[n][k] bf16, for 4 weights.
// grid (32, 32, 4), block 256 (= 32 x 8).
// ---------------------------------------------------------------------------
__global__ __launch_bounds__(256) void transpose4_kernel(
    const float* __restrict__ w0, const float* __restrict__ w1,
    const float* __restrict__ w2, const float* __restrict__ w3,
    ushort_t* __restrict__ o0, ushort_t* __restrict__ o1,
    ushort_t* __restrict__ o2, ushort_t* __restrict__ o3)
{
    __shared__ float tile[32][33];
    const float* W = (blockIdx.z == 0) ? w0 : (blockIdx.z == 1) ? w1
                   : (blockIdx.z == 2) ? w2 : w3;
    ushort_t* O = (blockIdx.z == 0) ? o0 : (blockIdx.z == 1) ? o1
                : (blockIdx.z == 2) ? o2 : o3;
    const int tx = threadIdx.x & 31;
    const int ty = threadIdx.x >> 5;     // 0..7
    const int kbase = blockIdx.y * 32;
    const int nbase = blockIdx.x * 32;
    #pragma unroll
    for (int j = 0; j < 4; ++j)
        tile[ty + 8 * j][tx] = W[(size_t)(kbase + ty + 8 * j) * 1024 + nbase + tx];
    __syncthreads();
    #pragma unroll
    for (int j = 0; j < 4; ++j) {
        int n = nbase + ty + 8 * j;
        O[(size_t)n * 1024 + kbase + tx] = f2bf(tile[tx][ty + 8 * j]);
    }
}

// ---------------------------------------------------------------------------
// bf16 MFMA GEMM (B^T layout): out[M,N] = A[M,K] @ Bt[N,K]^T + bvec (+res)
// BM=BN=64, BK=32, 256 threads (4 waves), wave-tile 32x32 (2x2 MFMAs of
// 16x16x32). global_load_lds width-16 staging, single-buffered.
// Grid: (N/64, M/64). 512 blocks -> 2 blocks/CU for latency hiding.
// ---------------------------------------------------------------------------
template <bool OUT_BF16, bool ADD_RES>
__global__ __launch_bounds__(256) void gemm_bt_mfma(
    const ushort_t* __restrict__ A, const ushort_t* __restrict__ Bt,
    const float* __restrict__ bvec, const float* __restrict__ res,
    void* __restrict__ outp, int M, int N, int K)
{
    __shared__ ushort_t As[64 * 32];   // [row][k] 4 KB
    __shared__ ushort_t Bs[64 * 32];   // [n][k]   4 KB

    const int tid = threadIdx.x;
    const int l = tid & 63;
    const int w = tid >> 6;            // wave 0..3
    const int wave_m = w >> 1;
    const int wave_n = w & 1;
    const int rowBase = blockIdx.y * 64;
    const int colBase = blockIdx.x * 64;

    // staging: wave w stages A-chunk w and B-chunk w (16 rows x 64 B each)
    const int srow = l >> 2;           // 0..15
    const int skof = (l & 3) * 8;      // ushort offset 0,8,16,24
    const ushort_t* gA = A  + (size_t)(rowBase + w * 16 + srow) * K + skof;
    const ushort_t* gB = Bt + (size_t)(colBase + w * 16 + srow) * K + skof;
    ushort_t* lA = As + w * 512;       // 1 KB chunks
    ushort_t* lB = Bs + w * 512;

    floatx4 acc[2][2];
    #pragma unroll
    for (int i = 0; i < 2; ++i)
        #pragma unroll
        for (int j = 0; j < 2; ++j)
            acc[i][j] = (floatx4){0.f, 0.f, 0.f, 0.f};

    const int fm = l & 15;
    const int fk = (l >> 4) * 8;

    for (int k0 = 0; k0 < K; k0 += 32) {
        __builtin_amdgcn_global_load_lds(
            (const __attribute__((address_space(1))) void*)(gA + k0),
            (__attribute__((address_space(3))) void*)lA, 16, 0, 0);
        __builtin_amdgcn_global_load_lds(
            (const __attribute__((address_space(1))) void*)(gB + k0),
            (__attribute__((address_space(3))) void*)lB, 16, 0, 0);
        __syncthreads();

        short8 afrag[2], bfrag[2];
        #pragma unroll
        for (int mi = 0; mi < 2; ++mi)
            afrag[mi] = *(const short8*)&As[(wave_m * 32 + mi * 16 + fm) * 32 + fk];
        #pragma unroll
        for (int ni = 0; ni < 2; ++ni)
            bfrag[ni] = *(const short8*)&Bs[(wave_n * 32 + ni * 16 + fm) * 32 + fk];

        #pragma unroll
        for (int mi = 0; mi < 2; ++mi)
            #pragma unroll
            for (int ni = 0; ni < 2; ++ni)
                acc[mi][ni] = __builtin_amdgcn_mfma_f32_16x16x32_bf16(
                    afrag[mi], bfrag[ni], acc[mi][ni], 0, 0, 0);
        __syncthreads();
    }

    // epilogue: C/D layout col=lane&15, row=(lane>>4)*4+reg
    const int crow0 = rowBase + wave_m * 32 + (l >> 4) * 4;
    const int ccol0 = colBase + wave_n * 32 + (l & 15);
    #pragma unroll
    for (int mi = 0; mi < 2; ++mi) {
        #pragma unroll
        for (int ni = 0; ni < 2; ++ni) {
            const int col = ccol0 + ni * 16;
            const float bb = bvec[col];
            #pragma unroll
            for (int r = 0; r < 4; ++r) {
                const int row = crow0 + mi * 16 + r;
                float v = acc[mi][ni][r] + bb;
                if (ADD_RES) v += res[(size_t)row * N + col];
                if (OUT_BF16)
                    ((ushort_t*)outp)[(size_t)row * N + col] = f2bf(v);
                else
                    ((float*)outp)[(size_t)row * N + col] = v;
            }
        }
    }
}

// ---------------------------------------------------------------------------
// Tiled attention (bf16 in/out): one block = 16 query rows x one (b,h).
// K staged transposed [d][k] (stride 66) fp32, V row-major (stride 68) fp32,
// scores in LDS fp32 [16][516]. 1/sum folded into PV epilogue.
// Grid: (LSEQ/16, BATCH*N_HEADS) = (32, 64).
// ---------------------------------------------------------------------------
__global__ __launch_bounds__(256) void attn_tiled(
    const ushort_t* __restrict__ qh, const ushort_t* __restrict__ kmat,
    const ushort_t* __restrict__ vmat, const float* __restrict__ bias,
    const float* __restrict__ gbias, ushort_t* __restrict__ ctx)
{
    __shared__ float Qs[16][64];
    __shared__ float S[16][516];
    __shared__ float KVu[64 * 68];
    __shared__ float red[16][17];
    __shared__ float rowmax[16];
    __shared__ float rowinv[16];

    const int tid = threadIdx.x;
    const int bh = blockIdx.y;
    const int h = bh & (N_HEADS - 1);
    const int b = bh >> 4;
    const int q0 = blockIdx.x * 16;

    const ushort_t* qbase = qh   + ((size_t)(b * LSEQ + q0)) * D_MODEL + h * DK;
    const ushort_t* kbase = kmat + ((size_t)(b * LSEQ)) * D_MODEL + h * DK;
    const ushort_t* vbase = vmat + ((size_t)(b * LSEQ)) * D_MODEL + h * DK;
    const size_t biasRow = ((size_t)bh * LSEQ + q0) * LSEQ;

    // ---- load Q tile (16x64), bf16 -> fp32 ----
    {
        int qr = tid >> 4, qd = (tid & 15) * 4;
        ushort4 t = *(const ushort4*)(qbase + (size_t)qr * D_MODEL + qd);
        Qs[qr][qd + 0] = bf2f(t.x);
        Qs[qr][qd + 1] = bf2f(t.y);
        Qs[qr][qd + 2] = bf2f(t.z);
        Qs[qr][qd + 3] = bf2f(t.w);
    }

    const int s_qg = tid >> 5;
    const int s_kg = tid & 31;
    const int sq_ = 2 * s_qg;

    for (int it = 0; it < 8; ++it) {
        const int k0 = it * 64;
        #pragma unroll
        for (int j = 0; j < 4; ++j) {
            int kk = (tid >> 4) + 16 * j;
            int dd = (tid & 15) * 4;
            ushort4 t = *(const ushort4*)(kbase + (size_t)(k0 + kk) * D_MODEL + dd);
            KVu[(dd + 0) * 66 + kk] = bf2f(t.x);
            KVu[(dd + 1) * 66 + kk] = bf2f(t.y);
            KVu[(dd + 2) * 66 + kk] = bf2f(t.z);
            KVu[(dd + 3) * 66 + kk] = bf2f(t.w);
        }
        __syncthreads();

        float acc00 = 0.f, acc01 = 0.f, acc10 = 0.f, acc11 = 0.f;
        #pragma unroll
        for (int d4 = 0; d4 < 64; d4 += 4) {
            float4 a0 = *(float4*)&Qs[sq_][d4];
            float4 a1 = *(float4*)&Qs[sq_ + 1][d4];
            float2 k0v = *(float2*)&KVu[(d4 + 0) * 66 + 2 * s_kg];
            float2 k1v = *(float2*)&KVu[(d4 + 1) * 66 + 2 * s_kg];
            float2 k2v = *(float2*)&KVu[(d4 + 2) * 66 + 2 * s_kg];
            float2 k3v = *(float2*)&KVu[(d4 + 3) * 66 + 2 * s_kg];
            acc00 += a0.x * k0v.x + a0.y * k1v.x + a0.z * k2v.x + a0.w * k3v.x;
            acc01 += a0.x * k0v.y + a0.y * k1v.y + a0.z * k2v.y + a0.w * k3v.y;
            acc10 += a1.x * k0v.x + a1.y * k1v.x + a1.z * k2v.x + a1.w * k3v.x;
            acc11 += a1.x * k0v.y + a1.y * k1v.y + a1.z * k2v.y + a1.w * k3v.y;
        }

        const int kglob = k0 + 2 * s_kg;
        float2 b0 = *(const float2*)(bias  + biasRow + (size_t)sq_ * LSEQ + kglob);
        float2 g0 = *(const float2*)(gbias + biasRow + (size_t)sq_ * LSEQ + kglob);
        float2 b1 = *(const float2*)(bias  + biasRow + (size_t)(sq_ + 1) * LSEQ + kglob);
        float2 g1 = *(const float2*)(gbias + biasRow + (size_t)(sq_ + 1) * LSEQ + kglob);
        float2 o0 = make_float2(acc00 * 0.125f + b0.x + g0.x, acc01 * 0.125f + b0.y + g0.y);
        float2 o1 = make_float2(acc10 * 0.125f + b1.x + g1.x, acc11 * 0.125f + b1.y + g1.y);
        *(float2*)&S[sq_][kglob] = o0;
        *(float2*)&S[sq_ + 1][kglob] = o1;
        __syncthreads();
    }

    // ---- softmax ----
    {
        const int sq = tid >> 4, sc = tid & 15;
        float m = -1e30f;
        #pragma unroll
        for (int i = 0; i < 32; ++i) m = fmaxf(m, S[sq][sc + 16 * i]);
        red[sq][sc] = m;
        __syncthreads();
        if (tid < 16) {
            float mm = red[tid][0];
            #pragma unroll
            for (int c = 1; c < 16; ++c) mm = fmaxf(mm, red[tid][c]);
            rowmax[tid] = mm;
        }
        __syncthreads();
        const float mx = rowmax[sq];
        float ssum = 0.f;
        #pragma unroll
        for (int i = 0; i < 32; ++i) {
            float e = __expf(S[sq][sc + 16 * i] - mx);
            S[sq][sc + 16 * i] = e;
            ssum += e;
        }
        red[sq][sc] = ssum;
        __syncthreads();
        if (tid < 16) {
            float t = 0.f;
            #pragma unroll
            for (int c = 0; c < 16; ++c) t += red[tid][c];
            rowinv[tid] = 1.0f / t;
        }
        __syncthreads();
    }

    // ---- PV ----
    const int p_qg = (tid >> 4) & 7;
    const int p_dg = tid & 15;
    const int p_kh = tid >> 7;
    const int pq = 2 * p_qg;
    const int pd = 4 * p_dg;
    float o0x = 0.f, o0y = 0.f, o0z = 0.f, o0w = 0.f;
    float o1x = 0.f, o1y = 0.f, o1z = 0.f, o1w = 0.f;

    for (int it = 0; it < 8; ++it) {
        const int k0 = it * 64;
        #pragma unroll
        for (int j = 0; j < 4; ++j) {
            int kk = (tid >> 4) + 16 * j;
            int dd = (tid & 15) * 4;
            ushort4 t = *(const ushort4*)(vbase + (size_t)(k0 + kk) * D_MODEL + dd);
            float4 f = make_float4(bf2f(t.x), bf2f(t.y), bf2f(t.z), bf2f(t.w));
            *(float4*)&KVu[kk * 68 + dd] = f;
        }
        __syncthreads();

        #pragma unroll
        for (int k4 = 0; k4 < 8; ++k4) {
            const int kl = 32 * p_kh + 4 * k4;
            float4 p0 = *(float4*)&S[pq][k0 + kl];
            float4 p1 = *(float4*)&S[pq + 1][k0 + kl];
            float4 v0 = *(float4*)&KVu[(kl + 0) * 68 + pd];
            float4 v1 = *(float4*)&KVu[(kl + 1) * 68 + pd];
            float4 v2 = *(float4*)&KVu[(kl + 2) * 68 + pd];
            float4 v3 = *(float4*)&KVu[(kl + 3) * 68 + pd];
            o0x += p0.x * v0.x + p0.y * v1.x + p0.z * v2.x + p0.w * v3.x;
            o0y += p0.x * v0.y + p0.y * v1.y + p0.z * v2.y + p0.w * v3.y;
            o0z += p0.x * v0.z + p0.y * v1.z + p0.z * v2.z + p0.w * v3.z;
            o0w += p0.x * v0.w + p0.y * v1.w + p0.z * v2.w + p0.w * v3.w;
            o1x += p1.x * v0.x + p1.y * v1.x + p1.z * v2.x + p1.w * v3.x;
            o1y += p1.x * v0.y + p1.y * v1.y + p1.z * v2.y + p1.w * v3.y;
            o1z += p1.x * v0.z + p1.y * v1.z + p1.z * v2.z + p1.w * v3.z;
            o1w += p1.x * v0.w + p1.y * v1.w + p1.z * v2.w + p1.w * v3.w;
        }
        __syncthreads();
    }

    if (p_kh == 1) {
        float* dst = &KVu[(size_t)(tid & 127) * 8];
        dst[0] = o0x; dst[1] = o0y; dst[2] = o0z; dst[3] = o0w;
        dst[4] = o1x; dst[5] = o1y; dst[6] = o1z; dst[7] = o1w;
    }
    __syncthreads();
    if (p_kh == 0) {
        const float* src = &KVu[(size_t)tid * 8];
        const float inv0 = rowinv[pq];
        const float inv1 = rowinv[pq + 1];
        ushort4 w0 = make_ushort4(f2bf((o0x + src[0]) * inv0), f2bf((o0y + src[1]) * inv0),
                                  f2bf((o0z + src[2]) * inv0), f2bf((o0w + src[3]) * inv0));
        ushort4 w1 = make_ushort4(f2bf((o1x + src[4]) * inv1), f2bf((o1y + src[5]) * inv1),
                                  f2bf((o1z + src[6]) * inv1), f2bf((o1w + src[7]) * inv1));
        ushort_t* crow0 = ctx + ((size_t)(b * LSEQ + q0 + pq)) * D_MODEL + h * DK + pd;
        ushort_t* crow1 = ctx + ((size_t)(b * LSEQ + q0 + pq + 1)) * D_MODEL + h * DK + pd;
        *(ushort4*)crow0 = w0;
        *(ushort4*)crow1 = w1;
    }
}

// ---------------------------------------------------------------------------
// In-place per-row LayerNorm over D=1024.
// ---------------------------------------------------------------------------
__global__ __launch_bounds__(256) void ln_kernel(
    float* __restrict__ x, const float* __restrict__ g,
    const float* __restrict__ beta)
{
    const int row = blockIdx.x;
    float* xr = x + (size_t)row * D_MODEL;
    const int tid = threadIdx.x;

    float v[4];
    float s = 0.f, sq = 0.f;
    #pragma unroll
    for (int j = 0; j < 4; ++j) {
        v[j] = xr[tid + 256 * j];
        s += v[j];
        sq += v[j] * v[j];
    }
    __shared__ float rs[256], rq[256];
    rs[tid] = s;
    rq[tid] = sq;
    __syncthreads();
    for (int st = 128; st > 0; st >>= 1) {
        if (tid < st) { rs[tid] += rs[tid + st]; rq[tid] += rq[tid + st]; }
        __syncthreads();
    }
    const float mean = rs[0] * (1.0f / D_MODEL);
    const float var = rq[0] * (1.0f / D_MODEL) - mean * mean;
    const float rinv = rsqrtf(var + 1e-6f);
    #pragma unroll
    for (int j = 0; j < 4; ++j) {
        int n = tid + 256 * j;
        xr[n] = (v[j] - mean) * rinv * g[n] + beta[n];
    }
}

// ---------------------------------------------------------------------------
extern "C" void kernel_launch(void* const* d_in, const int* in_sizes, int n_in,
                              void* d_out, int out_size, void* d_ws, size_t ws_size,
                              hipStream_t stream)
{
    const float* q     = (const float*)d_in[0];
    const float* k     = (const float*)d_in[1];
    const float* v     = (const float*)d_in[2];
    const float* bias  = (const float*)d_in[3];
    const float* gbias = (const float*)d_in[4];
    const float* wq    = (const float*)d_in[5];
    const float* bq    = (const float*)d_in[6];
    const float* wk    = (const float*)d_in[7];
    const float* bk    = (const float*)d_in[8];
    const float* wv    = (const float*)d_in[9];
    const float* bv    = (const float*)d_in[10];
    const float* wo    = (const float*)d_in[11];
    const float* bo    = (const float*)d_in[12];
    const float* ln_g  = (const float*)d_in[13];
    const float* ln_b  = (const float*)d_in[14];

    const size_t MB = 1u << 20;
    char* wsb = (char*)d_ws;
    // ws layout (28 MB total; previous rounds used 32 MB safely):
    ushort_t* vb   = (ushort_t*)(wsb + 0 * MB);    // 4 MB
    ushort_t* wqb  = (ushort_t*)(wsb + 4 * MB);    // 2 MB
    ushort_t* wkb  = (ushort_t*)(wsb + 6 * MB);
    ushort_t* wvb  = (ushort_t*)(wsb + 8 * MB);
    ushort_t* wob  = (ushort_t*)(wsb + 10 * MB);
    ushort_t* qhb  = (ushort_t*)(wsb + 12 * MB);   // 4 MB
    ushort_t* khb  = (ushort_t*)(wsb + 16 * MB);
    ushort_t* vhb  = (ushort_t*)(wsb + 20 * MB);
    ushort_t* ctxb = (ushort_t*)(wsb + 24 * MB);   // 4 MB
    // d_out (8 MB fp32) doubles as scratch for qb/kb; both dead before the
    // final GEMM overwrites d_out.
    ushort_t* qb = (ushort_t*)d_out;
    ushort_t* kb = (ushort_t*)d_out + (size_t)M_ROWS * D_MODEL;
    float* outp = (float*)d_out;

    const int NELEM = M_ROWS * D_MODEL;  // 2,097,152

    cast3_kernel<<<dim3(NELEM / 1024, 3), 256, 0, stream>>>(
        q, k, v, qb, kb, vb, NELEM);
    transpose4_kernel<<<dim3(32, 32, 4), 256, 0, stream>>>(
        wq, wk, wv, wo, wqb, wkb, wvb, wob);

    dim3 gblk(D_MODEL / 64, M_ROWS / 64);  // (16, 32) = 512 blocks
    gemm_bt_mfma<true, false><<<gblk, 256, 0, stream>>>(
        qb, wqb, bq, nullptr, qhb, M_ROWS, D_MODEL, D_MODEL);
    gemm_bt_mfma<true, false><<<gblk, 256, 0, stream>>>(
        kb, wkb, bk, nullptr, khb, M_ROWS, D_MODEL, D_MODEL);
    gemm_bt_mfma<true, false><<<gblk, 256, 0, stream>>>(
        vb, wvb, bv, nullptr, vhb, M_ROWS, D_MODEL, D_MODEL);

    dim3 ablk(LSEQ / 16, BATCH * N_HEADS);  // (32, 64)
    attn_tiled<<<ablk, 256, 0, stream>>>(qhb, khb, vhb, bias, gbias, ctxb);

    gemm_bt_mfma<false, true><<<gblk, 256, 0, stream>>>(
        ctxb, wob, bo, q, outp, M_ROWS, D_MODEL, D_MODEL);

    ln_kernel<<<M_ROWS, 256, 0, stream>>>(outp, ln_g, ln_b);
}

// Round 4
// 277.883 us; speedup vs baseline: 6.0274x; 1.3615x over previous
//
#include <hip/hip_runtime.h>

#define D_MODEL 1024
#define N_HEADS 16
#define DK 64
#define LSEQ 512
#define BATCH 4
#define M_ROWS (BATCH * LSEQ)   // 2048

typedef unsigned short ushort_t;
typedef __attribute__((ext_vector_type(8))) short short8;
typedef __attribute__((ext_vector_type(4))) float floatx4;

__device__ __forceinline__ float bf2f(unsigned short u) {
    return __uint_as_float(((unsigned int)u) << 16);
}
__device__ __forceinline__ unsigned short f2bf(float f) {
    unsigned int u = __float_as_uint(f);
    u += 0x7fffu + ((u >> 16) & 1u);   // round-to-nearest-even
    return (unsigned short)(u >> 16);
}

// ---------------------------------------------------------------------------
// cast3: three fp32 arrays -> bf16, 4 elems/thread. grid (n/1024, 3)
// ---------------------------------------------------------------------------
__global__ __launch_bounds__(256) void cast3_kernel(
    const float* __restrict__ a, const float* __restrict__ b,
    const float* __restrict__ c, ushort_t* __restrict__ oa,
    ushort_t* __restrict__ ob, ushort_t* __restrict__ oc, int n)
{
    const float* src = (blockIdx.y == 0) ? a : (blockIdx.y == 1) ? b : c;
    ushort_t* dst = (blockIdx.y == 0) ? oa : (blockIdx.y == 1) ? ob : oc;
    int i = (blockIdx.x * 256 + threadIdx.x) * 4;
    if (i + 3 < n) {
        float4 v = *(const float4*)(src + i);
        ushort4 o = make_ushort4(f2bf(v.x), f2bf(v.y), f2bf(v.z), f2bf(v.w));
        *(ushort4*)(dst + i) = o;
    }
}

// ---------------------------------------------------------------------------
// transpose4: W[k][n] fp32 (1024x1024) -> Wt[n][k] bf16, for 4 weights.
// ---------------------------------------------------------------------------
__global__ __launch_bounds__(256) void transpose4_kernel(
    const float* __restrict__ w0, const float* __restrict__ w1,
    const float* __restrict__ w2, const float* __restrict__ w3,
    ushort_t* __restrict__ o0, ushort_t* __restrict__ o1,
    ushort_t* __restrict__ o2, ushort_t* __restrict__ o3)
{
    __shared__ float tile[32][33];
    const float* W = (blockIdx.z == 0) ? w0 : (blockIdx.z == 1) ? w1
                   : (blockIdx.z == 2) ? w2 : w3;
    ushort_t* O = (blockIdx.z == 0) ? o0 : (blockIdx.z == 1) ? o1
                : (blockIdx.z == 2) ? o2 : o3;
    const int tx = threadIdx.x & 31;
    const int ty = threadIdx.x >> 5;
    const int kbase = blockIdx.y * 32;
    const int nbase = blockIdx.x * 32;
    #pragma unroll
    for (int j = 0; j < 4; ++j)
        tile[ty + 8 * j][tx] = W[(size_t)(kbase + ty + 8 * j) * 1024 + nbase + tx];
    __syncthreads();
    #pragma unroll
    for (int j = 0; j < 4; ++j) {
        int n = nbase + ty + 8 * j;
        O[(size_t)n * 1024 + kbase + tx] = f2bf(tile[tx][ty + 8 * j]);
    }
}

// ---------------------------------------------------------------------------
// bf16 MFMA GEMM body (B^T layout): out = A @ Bt^T + bvec (+res)
// BM=BN=64, BK=32, 256 threads, wave-tile 32x32 (2x2 of 16x16x32).
// ---------------------------------------------------------------------------
template <bool OUT_BF16, bool ADD_RES>
__device__ __forceinline__ void gemm_bt_body(
    const ushort_t* __restrict__ A, const ushort_t* __restrict__ Bt,
    const float* __restrict__ bvec, const float* __restrict__ res,
    void* __restrict__ outp, int M, int N, int K,
    int rowBase, int colBase, ushort_t* As, ushort_t* Bs)
{
    const int tid = threadIdx.x;
    const int l = tid & 63;
    const int w = tid >> 6;
    const int wave_m = w >> 1;
    const int wave_n = w & 1;

    const int srow = l >> 2;
    const int skof = (l & 3) * 8;
    const ushort_t* gA = A  + (size_t)(rowBase + w * 16 + srow) * K + skof;
    const ushort_t* gB = Bt + (size_t)(colBase + w * 16 + srow) * K + skof;
    ushort_t* lA = As + w * 512;
    ushort_t* lB = Bs + w * 512;

    floatx4 acc[2][2];
    #pragma unroll
    for (int i = 0; i < 2; ++i)
        #pragma unroll
        for (int j = 0; j < 2; ++j)
            acc[i][j] = (floatx4){0.f, 0.f, 0.f, 0.f};

    const int fm = l & 15;
    const int fk = (l >> 4) * 8;

    for (int k0 = 0; k0 < K; k0 += 32) {
        __builtin_amdgcn_global_load_lds(
            (const __attribute__((address_space(1))) void*)(gA + k0),
            (__attribute__((address_space(3))) void*)lA, 16, 0, 0);
        __builtin_amdgcn_global_load_lds(
            (const __attribute__((address_space(1))) void*)(gB + k0),
            (__attribute__((address_space(3))) void*)lB, 16, 0, 0);
        __syncthreads();

        short8 afrag[2], bfrag[2];
        #pragma unroll
        for (int mi = 0; mi < 2; ++mi)
            afrag[mi] = *(const short8*)&As[(wave_m * 32 + mi * 16 + fm) * 32 + fk];
        #pragma unroll
        for (int ni = 0; ni < 2; ++ni)
            bfrag[ni] = *(const short8*)&Bs[(wave_n * 32 + ni * 16 + fm) * 32 + fk];

        #pragma unroll
        for (int mi = 0; mi < 2; ++mi)
            #pragma unroll
            for (int ni = 0; ni < 2; ++ni)
                acc[mi][ni] = __builtin_amdgcn_mfma_f32_16x16x32_bf16(
                    afrag[mi], bfrag[ni], acc[mi][ni], 0, 0, 0);
        __syncthreads();
    }

    const int crow0 = rowBase + wave_m * 32 + (l >> 4) * 4;
    const int ccol0 = colBase + wave_n * 32 + (l & 15);
    #pragma unroll
    for (int mi = 0; mi < 2; ++mi) {
        #pragma unroll
        for (int ni = 0; ni < 2; ++ni) {
            const int col = ccol0 + ni * 16;
            const float bb = bvec[col];
            #pragma unroll
            for (int r = 0; r < 4; ++r) {
                const int row = crow0 + mi * 16 + r;
                float v = acc[mi][ni][r] + bb;
                if (ADD_RES) v += res[(size_t)row * N + col];
                if (OUT_BF16)
                    ((ushort_t*)outp)[(size_t)row * N + col] = f2bf(v);
                else
                    ((float*)outp)[(size_t)row * N + col] = v;
            }
        }
    }
}

// Batched QKV projection: blockIdx.z selects (A, Bt, bias, out). 1536 blocks.
__global__ __launch_bounds__(256) void gemm_qkv(
    const ushort_t* a0, const ushort_t* a1, const ushort_t* a2,
    const ushort_t* t0, const ushort_t* t1, const ushort_t* t2,
    const float* b0, const float* b1, const float* b2,
    ushort_t* o0, ushort_t* o1, ushort_t* o2)
{
    __shared__ ushort_t As[64 * 32];
    __shared__ ushort_t Bs[64 * 32];
    const int z = blockIdx.z;
    const ushort_t* A  = (z == 0) ? a0 : (z == 1) ? a1 : a2;
    const ushort_t* Bt = (z == 0) ? t0 : (z == 1) ? t1 : t2;
    const float* bv    = (z == 0) ? b0 : (z == 1) ? b1 : b2;
    ushort_t* o        = (z == 0) ? o0 : (z == 1) ? o1 : o2;
    gemm_bt_body<true, false>(A, Bt, bv, nullptr, o, M_ROWS, D_MODEL, D_MODEL,
                              blockIdx.y * 64, blockIdx.x * 64, As, Bs);
}

// Final projection + residual, fp32 out.
__global__ __launch_bounds__(256) void gemm_out(
    const ushort_t* __restrict__ A, const ushort_t* __restrict__ Bt,
    const float* __restrict__ bvec, const float* __restrict__ res,
    float* __restrict__ outp)
{
    __shared__ ushort_t As[64 * 32];
    __shared__ ushort_t Bs[64 * 32];
    gemm_bt_body<false, true>(A, Bt, bvec, res, outp, M_ROWS, D_MODEL, D_MODEL,
                              blockIdx.y * 64, blockIdx.x * 64, As, Bs);
}

// ---------------------------------------------------------------------------
// MFMA attention: block = 16 q-rows x one (b,h). 256 threads (4 waves).
// Pass 1: S = QK^T/8 + bias + gbias via mfma (K frags direct from global,
//         no barriers in k-loop), S fp32 in LDS (stride 516 -> 2-way free).
// Softmax: exact, P repacked bf16 in-place over S (packed dwords).
// Pass 2: ctx = P V via mfma; V transposed into LDS per 64-key tile
//         (packed-dword writes). 1/sum folded into epilogue.
// Grid: (LSEQ/16, BATCH*N_HEADS) = (32, 64) = 2048 blocks, ~45.8 KB LDS.
// ---------------------------------------------------------------------------
__global__ __launch_bounds__(256) void attn_mfma(
    const ushort_t* __restrict__ qh, const ushort_t* __restrict__ kh,
    const ushort_t* __restrict__ vh, const float* __restrict__ bias,
    const float* __restrict__ gbias, ushort_t* __restrict__ ctx)
{
    __shared__ ushort_t Qs[16 * 72];     // stride 72 (144 B, 16B-aligned rows)
    __shared__ float S[16 * 516];        // raw scores; later P packed bf16
    __shared__ float Vt[64 * 36];        // V^T packed dwords, stride 36
    __shared__ float red[16][17];
    __shared__ float rowmax[16];
    __shared__ float rowinv[16];

    const int tid = threadIdx.x;
    const int l = tid & 63;
    const int w = tid >> 6;
    const int m = l & 15;
    const int g = l >> 4;

    const int bh = blockIdx.y;
    const int h = bh & (N_HEADS - 1);
    const int b = bh >> 4;
    const int q0 = blockIdx.x * 16;

    const ushort_t* Qg = qh + ((size_t)(b * LSEQ + q0)) * D_MODEL + h * DK;
    const ushort_t* Kg = kh + ((size_t)(b * LSEQ)) * D_MODEL + h * DK;
    const ushort_t* Vg = vh + ((size_t)(b * LSEQ)) * D_MODEL + h * DK;
    const float* biasp  = bias  + ((size_t)bh * LSEQ + q0) * LSEQ;
    const float* gbiasp = gbias + ((size_t)bh * LSEQ + q0) * LSEQ;

    // ---- stage Q tile (16 x 64 bf16) ----
    if (tid < 128) {
        int row = tid >> 3, seg = tid & 7;
        short8 t = *(const short8*)(Qg + (size_t)row * D_MODEL + seg * 8);
        *(short8*)&Qs[row * 72 + seg * 8] = t;
    }
    __syncthreads();

    short8 aq0 = *(const short8*)&Qs[m * 72 + g * 8];
    short8 aq1 = *(const short8*)&Qs[m * 72 + g * 8 + 32];

    // ---- pass 1: scores (no barriers in loop) ----
    #pragma unroll 2
    for (int it = 0; it < 8; ++it) {
        const int kb = it * 64 + w * 16;            // this wave's key base
        const ushort_t* kr = Kg + (size_t)(kb + m) * D_MODEL + g * 8;
        short8 bk0 = *(const short8*)kr;
        short8 bk1 = *(const short8*)(kr + 32);
        floatx4 acc = (floatx4){0.f, 0.f, 0.f, 0.f};
        acc = __builtin_amdgcn_mfma_f32_16x16x32_bf16(aq0, bk0, acc, 0, 0, 0);
        acc = __builtin_amdgcn_mfma_f32_16x16x32_bf16(aq1, bk1, acc, 0, 0, 0);
        const int col = kb + m;                     // key index (= C col)
        const int qrow0 = g * 4;
        const float* bp = biasp  + (size_t)qrow0 * LSEQ + col;
        const float* gp = gbiasp + (size_t)qrow0 * LSEQ + col;
        #pragma unroll
        for (int r = 0; r < 4; ++r) {
            float v = acc[r] * 0.125f + bp[(size_t)r * LSEQ] + gp[(size_t)r * LSEQ];
            S[(qrow0 + r) * 516 + col] = v;
        }
    }
    __syncthreads();

    // ---- softmax (exact); pack P to bf16 in-place over S ----
    {
        const int row = tid >> 4, sc = tid & 15;
        float* Srow = &S[row * 516];
        float mx = -1e30f;
        #pragma unroll
        for (int i = 0; i < 16; ++i) {
            float2 v = *(float2*)&Srow[2 * sc + 32 * i];
            mx = fmaxf(mx, fmaxf(v.x, v.y));
        }
        red[row][sc] = mx;
        __syncthreads();
        if (tid < 16) {
            float mm = red[tid][0];
            #pragma unroll
            for (int c = 1; c < 16; ++c) mm = fmaxf(mm, red[tid][c]);
            rowmax[tid] = mm;
        }
        __syncthreads();
        mx = rowmax[row];
        float sum = 0.f;
        unsigned pk[16];
        #pragma unroll
        for (int i = 0; i < 16; ++i) {
            float2 v = *(float2*)&Srow[2 * sc + 32 * i];
            float e0 = __expf(v.x - mx);
            float e1 = __expf(v.y - mx);
            sum += e0 + e1;
            pk[i] = (unsigned)f2bf(e0) | ((unsigned)f2bf(e1) << 16);
        }
        red[row][sc] = sum;
        __syncthreads();                 // all S reads done; red visible
        if (tid < 16) {
            float t = 0.f;
            #pragma unroll
            for (int c = 0; c < 16; ++c) t += red[tid][c];
            rowinv[tid] = 1.0f / t;
        }
        unsigned* Pd = (unsigned*)Srow;
        #pragma unroll
        for (int i = 0; i < 16; ++i)
            Pd[sc + 16 * i] = pk[i];     // dword idx = key/2
    }

    // ---- pass 2: ctx = P V ----
    const ushort_t* Ps = (const ushort_t*)S;   // row stride 1032 ushorts
    floatx4 oacc = (floatx4){0.f, 0.f, 0.f, 0.f};
    const unsigned* VtD = (const unsigned*)Vt;

    for (int vt = 0; vt < 8; ++vt) {
        const int kv0 = vt * 64;
        __syncthreads();                 // prior frag reads / Pb writes done
        {
            const int kp = tid & 31, dg = tid >> 5;
            const ushort_t* vr = Vg + (size_t)(kv0 + 2 * kp) * D_MODEL + dg * 8;
            short8 r0 = *(const short8*)vr;
            short8 r1 = *(const short8*)(vr + D_MODEL);
            unsigned* vtp = (unsigned*)Vt;
            #pragma unroll
            for (int i = 0; i < 8; ++i) {
                unsigned dwv = (unsigned)(ushort_t)r0[i]
                             | ((unsigned)(ushort_t)r1[i] << 16);
                vtp[(dg * 8 + i) * 36 + kp] = dwv;
            }
        }
        __syncthreads();
        #pragma unroll
        for (int kt = 0; kt < 2; ++kt) {
            short8 pf = *(const short8*)&Ps[(size_t)m * 1032 + kv0 + kt * 32 + g * 8];
            short8 vf = *(const short8*)&VtD[(w * 16 + m) * 36 + kt * 16 + g * 4];
            oacc = __builtin_amdgcn_mfma_f32_16x16x32_bf16(pf, vf, oacc, 0, 0, 0);
        }
    }

    // ---- epilogue: scale by 1/sum, write ctx bf16 ----
    {
        const int qrow0 = g * 4;
        const int dcol = w * 16 + m;
        ushort_t* cp = ctx + ((size_t)(b * LSEQ + q0 + qrow0)) * D_MODEL + h * DK + dcol;
        #pragma unroll
        for (int r = 0; r < 4; ++r)
            cp[(size_t)r * D_MODEL] = f2bf(oacc[r] * rowinv[qrow0 + r]);
    }
}

// ---------------------------------------------------------------------------
// In-place per-row LayerNorm over D=1024.
// ---------------------------------------------------------------------------
__global__ __launch_bounds__(256) void ln_kernel(
    float* __restrict__ x, const float* __restrict__ g,
    const float* __restrict__ beta)
{
    const int row = blockIdx.x;
    float* xr = x + (size_t)row * D_MODEL;
    const int tid = threadIdx.x;

    float v[4];
    float s = 0.f, sq = 0.f;
    #pragma unroll
    for (int j = 0; j < 4; ++j) {
        v[j] = xr[tid + 256 * j];
        s += v[j];
        sq += v[j] * v[j];
    }
    __shared__ float rs[256], rq[256];
    rs[tid] = s;
    rq[tid] = sq;
    __syncthreads();
    for (int st = 128; st > 0; st >>= 1) {
        if (tid < st) { rs[tid] += rs[tid + st]; rq[tid] += rq[tid + st]; }
        __syncthreads();
    }
    const float mean = rs[0] * (1.0f / D_MODEL);
    const float var = rq[0] * (1.0f / D_MODEL) - mean * mean;
    const float rinv = rsqrtf(var + 1e-6f);
    #pragma unroll
    for (int j = 0; j < 4; ++j) {
        int n = tid + 256 * j;
        xr[n] = (v[j] - mean) * rinv * g[n] + beta[n];
    }
}

// ---------------------------------------------------------------------------
extern "C" void kernel_launch(void* const* d_in, const int* in_sizes, int n_in,
                              void* d_out, int out_size, void* d_ws, size_t ws_size,
                              hipStream_t stream)
{
    const float* q     = (const float*)d_in[0];
    const float* k     = (const float*)d_in[1];
    const float* v     = (const float*)d_in[2];
    const float* bias  = (const float*)d_in[3];
    const float* gbias = (const float*)d_in[4];
    const float* wq    = (const float*)d_in[5];
    const float* bq    = (const float*)d_in[6];
    const float* wk    = (const float*)d_in[7];
    const float* bk    = (const float*)d_in[8];
    const float* wv    = (const float*)d_in[9];
    const float* bv    = (const float*)d_in[10];
    const float* wo    = (const float*)d_in[11];
    const float* bo    = (const float*)d_in[12];
    const float* ln_g  = (const float*)d_in[13];
    const float* ln_b  = (const float*)d_in[14];

    const size_t MB = 1u << 20;
    char* wsb = (char*)d_ws;
    ushort_t* vb   = (ushort_t*)(wsb + 0 * MB);    // 4 MB
    ushort_t* wqb  = (ushort_t*)(wsb + 4 * MB);    // 2 MB each
    ushort_t* wkb  = (ushort_t*)(wsb + 6 * MB);
    ushort_t* wvb  = (ushort_t*)(wsb + 8 * MB);
    ushort_t* wob  = (ushort_t*)(wsb + 10 * MB);
    ushort_t* qhb  = (ushort_t*)(wsb + 12 * MB);   // 4 MB each
    ushort_t* khb  = (ushort_t*)(wsb + 16 * MB);
    ushort_t* vhb  = (ushort_t*)(wsb + 20 * MB);
    ushort_t* ctxb = (ushort_t*)(wsb + 24 * MB);
    // d_out doubles as qb/kb scratch; dead before final GEMM writes d_out.
    ushort_t* qb = (ushort_t*)d_out;
    ushort_t* kb = (ushort_t*)d_out + (size_t)M_ROWS * D_MODEL;
    float* outp = (float*)d_out;

    const int NELEM = M_ROWS * D_MODEL;

    cast3_kernel<<<dim3(NELEM / 1024, 3), 256, 0, stream>>>(
        q, k, v, qb, kb, vb, NELEM);
    transpose4_kernel<<<dim3(32, 32, 4), 256, 0, stream>>>(
        wq, wk, wv, wo, wqb, wkb, wvb, wob);

    dim3 gqkv(D_MODEL / 64, M_ROWS / 64, 3);  // (16, 32, 3) = 1536 blocks
    gemm_qkv<<<gqkv, 256, 0, stream>>>(
        qb, kb, vb, wqb, wkb, wvb, bq, bk, bv, qhb, khb, vhb);

    dim3 ablk(LSEQ / 16, BATCH * N_HEADS);    // (32, 64) = 2048 blocks
    attn_mfma<<<ablk, 256, 0, stream>>>(qhb, khb, vhb, bias, gbias, ctxb);

    dim3 gout(D_MODEL / 64, M_ROWS / 64);     // (16, 32)
    gemm_out<<<gout, 256, 0, stream>>>(ctxb, wob, bo, q, outp);

    ln_kernel<<<M_ROWS, 256, 0, stream>>>(outp, ln_g, ln_b);
}

// Round 5
// 271.993 us; speedup vs baseline: 6.1580x; 1.0217x over previous
//
#include <hip/hip_runtime.h>

#define D_MODEL 1024
#define N_HEADS 16
#define DK 64
#define LSEQ 512
#define BATCH 4
#define M_ROWS (BATCH * LSEQ)   // 2048

typedef unsigned short ushort_t;
typedef __attribute__((ext_vector_type(8))) short short8;
typedef __attribute__((ext_vector_type(4))) float floatx4;

__device__ __forceinline__ float bf2f(unsigned short u) {
    return __uint_as_float(((unsigned int)u) << 16);
}
__device__ __forceinline__ unsigned short f2bf(float f) {
    unsigned int u = __float_as_uint(f);
    u += 0x7fffu + ((u >> 16) & 1u);   // round-to-nearest-even
    return (unsigned short)(u >> 16);
}

// ---------------------------------------------------------------------------
// cast3: three fp32 arrays -> bf16, 4 elems/thread. grid (n/1024, 3)
// ---------------------------------------------------------------------------
__global__ __launch_bounds__(256) void cast3_kernel(
    const float* __restrict__ a, const float* __restrict__ b,
    const float* __restrict__ c, ushort_t* __restrict__ oa,
    ushort_t* __restrict__ ob, ushort_t* __restrict__ oc, int n)
{
    const float* src = (blockIdx.y == 0) ? a : (blockIdx.y == 1) ? b : c;
    ushort_t* dst = (blockIdx.y == 0) ? oa : (blockIdx.y == 1) ? ob : oc;
    int i = (blockIdx.x * 256 + threadIdx.x) * 4;
    if (i + 3 < n) {
        float4 v = *(const float4*)(src + i);
        ushort4 o = make_ushort4(f2bf(v.x), f2bf(v.y), f2bf(v.z), f2bf(v.w));
        *(ushort4*)(dst + i) = o;
    }
}

// ---------------------------------------------------------------------------
// transpose4: W[k][n] fp32 (1024x1024) -> Wt[n][k] bf16, for 4 weights.
// ---------------------------------------------------------------------------
__global__ __launch_bounds__(256) void transpose4_kernel(
    const float* __restrict__ w0, const float* __restrict__ w1,
    const float* __restrict__ w2, const float* __restrict__ w3,
    ushort_t* __restrict__ o0, ushort_t* __restrict__ o1,
    ushort_t* __restrict__ o2, ushort_t* __restrict__ o3)
{
    __shared__ float tile[32][33];
    const float* W = (blockIdx.z == 0) ? w0 : (blockIdx.z == 1) ? w1
                   : (blockIdx.z == 2) ? w2 : w3;
    ushort_t* O = (blockIdx.z == 0) ? o0 : (blockIdx.z == 1) ? o1
                : (blockIdx.z == 2) ? o2 : o3;
    const int tx = threadIdx.x & 31;
    const int ty = threadIdx.x >> 5;
    const int kbase = blockIdx.y * 32;
    const int nbase = blockIdx.x * 32;
    #pragma unroll
    for (int j = 0; j < 4; ++j)
        tile[ty + 8 * j][tx] = W[(size_t)(kbase + ty + 8 * j) * 1024 + nbase + tx];
    __syncthreads();
    #pragma unroll
    for (int j = 0; j < 4; ++j) {
        int n = nbase + ty + 8 * j;
        O[(size_t)n * 1024 + kbase + tx] = f2bf(tile[tx][ty + 8 * j]);
    }
}

// ---------------------------------------------------------------------------
// bf16 MFMA GEMM body (B^T layout): out = A @ Bt^T [+ bvec] [+ res]
// BM=BN=64, BK=64, 256 threads, wave-tile 32x32 (2x2x2 of 16x16x32).
// LDS tiles stored with per-row chunk rotation (position p of row r holds
// global k-chunk (p+r)&7) so ds_read_b128 frag reads are bank-balanced while
// staying compatible with global_load_lds's fixed lane*16 destination map.
// ---------------------------------------------------------------------------
template <bool OUT_BF16, bool ADD_BVEC, bool ADD_RES>
__device__ __forceinline__ void gemm_bt_body(
    const ushort_t* __restrict__ A, const ushort_t* __restrict__ Bt,
    const float* __restrict__ bvec, const float* __restrict__ res,
    void* __restrict__ outp, int N, int K, int kStart, int kEnd,
    int rowBase, int colBase, ushort_t* As, ushort_t* Bs)
{
    const int tid = threadIdx.x;
    const int l = tid & 63;
    const int w = tid >> 6;
    const int wave_m = w >> 1;
    const int wave_n = w & 1;

    // staging: wave w covers 16 rows of A and Bt via 2 insts of 8 rows each.
    // lane l -> row8 = l>>3, lds chunk position p = l&7, global chunk (p+row8)&7
    const int srow8 = l >> 3;
    const int cgl = ((l & 7) + srow8) & 7;        // global k-chunk
    const ushort_t* gA0 = A  + (size_t)(rowBase + w * 16 + 0 + srow8) * K + cgl * 8;
    const ushort_t* gA1 = A  + (size_t)(rowBase + w * 16 + 8 + srow8) * K + cgl * 8;
    const ushort_t* gB0 = Bt + (size_t)(colBase + w * 16 + 0 + srow8) * K + cgl * 8;
    const ushort_t* gB1 = Bt + (size_t)(colBase + w * 16 + 8 + srow8) * K + cgl * 8;
    ushort_t* lA0 = As + w * 1024;
    ushort_t* lA1 = As + w * 1024 + 512;
    ushort_t* lB0 = Bs + w * 1024;
    ushort_t* lB1 = Bs + w * 1024 + 512;

    floatx4 acc[2][2];
    #pragma unroll
    for (int i = 0; i < 2; ++i)
        #pragma unroll
        for (int j = 0; j < 2; ++j)
            acc[i][j] = (floatx4){0.f, 0.f, 0.f, 0.f};

    const int fm = l & 15;
    const int fg = l >> 4;

    for (int k0 = kStart; k0 < kEnd; k0 += 64) {
        __builtin_amdgcn_global_load_lds(
            (const __attribute__((address_space(1))) void*)(gA0 + k0),
            (__attribute__((address_space(3))) void*)lA0, 16, 0, 0);
        __builtin_amdgcn_global_load_lds(
            (const __attribute__((address_space(1))) void*)(gA1 + k0),
            (__attribute__((address_space(3))) void*)lA1, 16, 0, 0);
        __builtin_amdgcn_global_load_lds(
            (const __attribute__((address_space(1))) void*)(gB0 + k0),
            (__attribute__((address_space(3))) void*)lB0, 16, 0, 0);
        __builtin_amdgcn_global_load_lds(
            (const __attribute__((address_space(1))) void*)(gB1 + k0),
            (__attribute__((address_space(3))) void*)lB1, 16, 0, 0);
        __syncthreads();

        short8 afrag[2][2], bfrag[2][2];
        #pragma unroll
        for (int mi = 0; mi < 2; ++mi)
            #pragma unroll
            for (int kt = 0; kt < 2; ++kt) {
                int p = ((kt * 4 + fg) - fm) & 7;
                afrag[mi][kt] = *(const short8*)
                    &As[(wave_m * 32 + mi * 16 + fm) * 64 + p * 8];
            }
        #pragma unroll
        for (int ni = 0; ni < 2; ++ni)
            #pragma unroll
            for (int kt = 0; kt < 2; ++kt) {
                int p = ((kt * 4 + fg) - fm) & 7;
                bfrag[ni][kt] = *(const short8*)
                    &Bs[(wave_n * 32 + ni * 16 + fm) * 64 + p * 8];
            }

        #pragma unroll
        for (int kt = 0; kt < 2; ++kt)
            #pragma unroll
            for (int mi = 0; mi < 2; ++mi)
                #pragma unroll
                for (int ni = 0; ni < 2; ++ni)
                    acc[mi][ni] = __builtin_amdgcn_mfma_f32_16x16x32_bf16(
                        afrag[mi][kt], bfrag[ni][kt], acc[mi][ni], 0, 0, 0);
        __syncthreads();
    }

    const int crow0 = rowBase + wave_m * 32 + fg * 4;
    const int ccol0 = colBase + wave_n * 32 + fm;
    #pragma unroll
    for (int mi = 0; mi < 2; ++mi) {
        #pragma unroll
        for (int ni = 0; ni < 2; ++ni) {
            const int col = ccol0 + ni * 16;
            const float bb = ADD_BVEC ? bvec[col] : 0.f;
            #pragma unroll
            for (int r = 0; r < 4; ++r) {
                const int row = crow0 + mi * 16 + r;
                float v = acc[mi][ni][r] + bb;
                if (ADD_RES) v += res[(size_t)row * N + col];
                if (OUT_BF16)
                    ((ushort_t*)outp)[(size_t)row * N + col] = f2bf(v);
                else
                    ((float*)outp)[(size_t)row * N + col] = v;
            }
        }
    }
}

// Batched QKV projection: blockIdx.z selects (A, Bt, bias, out). 1536 blocks.
__global__ __launch_bounds__(256) void gemm_qkv(
    const ushort_t* a0, const ushort_t* a1, const ushort_t* a2,
    const ushort_t* t0, const ushort_t* t1, const ushort_t* t2,
    const float* b0, const float* b1, const float* b2,
    ushort_t* o0, ushort_t* o1, ushort_t* o2)
{
    __shared__ ushort_t As[64 * 64];
    __shared__ ushort_t Bs[64 * 64];
    const int z = blockIdx.z;
    const ushort_t* A  = (z == 0) ? a0 : (z == 1) ? a1 : a2;
    const ushort_t* Bt = (z == 0) ? t0 : (z == 1) ? t1 : t2;
    const float* bv    = (z == 0) ? b0 : (z == 1) ? b1 : b2;
    ushort_t* o        = (z == 0) ? o0 : (z == 1) ? o1 : o2;
    gemm_bt_body<true, true, false>(A, Bt, bv, nullptr, o, D_MODEL, D_MODEL,
                                    0, D_MODEL,
                                    blockIdx.y * 64, blockIdx.x * 64, As, Bs);
}

// Final projection, split-K x2: z=0 -> K[0,512) + bias + residual -> d_out,
// z=1 -> K[512,1024) partial -> out1. ln_kernel sums them.
__global__ __launch_bounds__(256) void gemm_out(
    const ushort_t* __restrict__ A, const ushort_t* __restrict__ Bt,
    const float* __restrict__ bvec, const float* __restrict__ res,
    float* __restrict__ out0, float* __restrict__ out1)
{
    __shared__ ushort_t As[64 * 64];
    __shared__ ushort_t Bs[64 * 64];
    if (blockIdx.z == 0)
        gemm_bt_body<false, true, true>(A, Bt, bvec, res, out0, D_MODEL,
                                        D_MODEL, 0, 512,
                                        blockIdx.y * 64, blockIdx.x * 64, As, Bs);
    else
        gemm_bt_body<false, false, false>(A, Bt, nullptr, nullptr, out1, D_MODEL,
                                          D_MODEL, 512, 1024,
                                          blockIdx.y * 64, blockIdx.x * 64, As, Bs);
}

// ---------------------------------------------------------------------------
// MFMA attention: block = 16 q-rows x one (b,h). 256 threads (4 waves).
// Pass 1: raw S = QK^T/8 via mfma (K frags direct from global, barrier-free).
// Bias phase: thread (row,s) streams bias+gbias as 16 independent float4
//   loads (coalesced, deep ILP), adds to S kept in registers.
// Softmax: exact; P packed bf16 in-place over S (dword idx = key/2).
// Pass 2: ctx = P V via mfma; V transposed into LDS per 64-key tile.
// Grid: (LSEQ/16, BATCH*N_HEADS) = (32, 64), ~45.8 KB LDS, 3 blocks/CU.
// ---------------------------------------------------------------------------
__global__ __launch_bounds__(256) void attn_mfma(
    const ushort_t* __restrict__ qh, const ushort_t* __restrict__ kh,
    const ushort_t* __restrict__ vh, const float* __restrict__ bias,
    const float* __restrict__ gbias, ushort_t* __restrict__ ctx)
{
    __shared__ ushort_t Qs[16 * 72];
    __shared__ float S[16 * 516];        // raw scores; later P packed bf16
    __shared__ float Vt[64 * 36];        // V^T packed dwords, stride 36
    __shared__ float red[16][17];
    __shared__ float rowmax[16];
    __shared__ float rowinv[16];

    const int tid = threadIdx.x;
    const int l = tid & 63;
    const int w = tid >> 6;
    const int m = l & 15;
    const int g = l >> 4;

    const int bh = blockIdx.y;
    const int h = bh & (N_HEADS - 1);
    const int b = bh >> 4;
    const int q0 = blockIdx.x * 16;

    const ushort_t* Qg = qh + ((size_t)(b * LSEQ + q0)) * D_MODEL + h * DK;
    const ushort_t* Kg = kh + ((size_t)(b * LSEQ)) * D_MODEL + h * DK;
    const ushort_t* Vg = vh + ((size_t)(b * LSEQ)) * D_MODEL + h * DK;

    // ---- stage Q tile (16 x 64 bf16) ----
    if (tid < 128) {
        int row = tid >> 3, seg = tid & 7;
        short8 t = *(const short8*)(Qg + (size_t)row * D_MODEL + seg * 8);
        *(short8*)&Qs[row * 72 + seg * 8] = t;
    }
    __syncthreads();

    short8 aq0 = *(const short8*)&Qs[m * 72 + g * 8];
    short8 aq1 = *(const short8*)&Qs[m * 72 + g * 8 + 32];

    // ---- pass 1: raw scores (no barriers in loop) ----
    #pragma unroll 2
    for (int it = 0; it < 8; ++it) {
        const int kb = it * 64 + w * 16;
        const ushort_t* kr = Kg + (size_t)(kb + m) * D_MODEL + g * 8;
        short8 bk0 = *(const short8*)kr;
        short8 bk1 = *(const short8*)(kr + 32);
        floatx4 acc = (floatx4){0.f, 0.f, 0.f, 0.f};
        acc = __builtin_amdgcn_mfma_f32_16x16x32_bf16(aq0, bk0, acc, 0, 0, 0);
        acc = __builtin_amdgcn_mfma_f32_16x16x32_bf16(aq1, bk1, acc, 0, 0, 0);
        const int col = kb + m;
        const int qrow0 = g * 4;
        #pragma unroll
        for (int r = 0; r < 4; ++r)
            S[(qrow0 + r) * 516 + col] = acc[r] * 0.125f;
    }
    __syncthreads();

    // ---- bias phase + softmax; thread (row,s) owns cols 4s+64i ----
    {
        const int row = tid >> 4, s = tid & 15;
        float* Srow = &S[row * 516];
        const float* bp = bias  + ((size_t)bh * LSEQ + q0 + row) * LSEQ;
        const float* gp = gbias + ((size_t)bh * LSEQ + q0 + row) * LSEQ;

        float4 vv[8];
        float mx = -1e30f;
        #pragma unroll
        for (int i = 0; i < 8; ++i) {
            const int col = 4 * s + 64 * i;
            float4 sv = *(const float4*)&Srow[col];
            float4 bb = *(const float4*)(bp + col);
            float4 gg = *(const float4*)(gp + col);
            float4 v = make_float4(sv.x + bb.x + gg.x, sv.y + bb.y + gg.y,
                                   sv.z + bb.z + gg.z, sv.w + bb.w + gg.w);
            vv[i] = v;
            mx = fmaxf(mx, fmaxf(fmaxf(v.x, v.y), fmaxf(v.z, v.w)));
        }
        red[row][s] = mx;
        __syncthreads();
        if (tid < 16) {
            float mm = red[tid][0];
            #pragma unroll
            for (int c = 1; c < 16; ++c) mm = fmaxf(mm, red[tid][c]);
            rowmax[tid] = mm;
        }
        __syncthreads();
        mx = rowmax[row];

        float sum = 0.f;
        unsigned* Pd = (unsigned*)Srow;
        #pragma unroll
        for (int i = 0; i < 8; ++i) {
            float e0 = __expf(vv[i].x - mx);
            float e1 = __expf(vv[i].y - mx);
            float e2 = __expf(vv[i].z - mx);
            float e3 = __expf(vv[i].w - mx);
            sum += (e0 + e1) + (e2 + e3);
            Pd[2 * s + 32 * i]     = (unsigned)f2bf(e0) | ((unsigned)f2bf(e1) << 16);
            Pd[2 * s + 32 * i + 1] = (unsigned)f2bf(e2) | ((unsigned)f2bf(e3) << 16);
        }
        red[row][s] = sum;
        __syncthreads();
        if (tid < 16) {
            float t = 0.f;
            #pragma unroll
            for (int c = 0; c < 16; ++c) t += red[tid][c];
            rowinv[tid] = 1.0f / t;
        }
    }

    // ---- pass 2: ctx = P V ----
    const ushort_t* Ps = (const ushort_t*)S;   // ushort idx = key, row stride 1032
    floatx4 oacc = (floatx4){0.f, 0.f, 0.f, 0.f};
    const unsigned* VtD = (const unsigned*)Vt;

    for (int vt = 0; vt < 8; ++vt) {
        const int kv0 = vt * 64;
        __syncthreads();
        {
            const int kp = tid & 31, dg = tid >> 5;
            const ushort_t* vr = Vg + (size_t)(kv0 + 2 * kp) * D_MODEL + dg * 8;
            short8 r0 = *(const short8*)vr;
            short8 r1 = *(const short8*)(vr + D_MODEL);
            unsigned* vtp = (unsigned*)Vt;
            #pragma unroll
            for (int i = 0; i < 8; ++i) {
                unsigned dwv = (unsigned)(ushort_t)r0[i]
                             | ((unsigned)(ushort_t)r1[i] << 16);
                vtp[(dg * 8 + i) * 36 + kp] = dwv;
            }
        }
        __syncthreads();
        #pragma unroll
        for (int kt = 0; kt < 2; ++kt) {
            short8 pf = *(const short8*)&Ps[(size_t)m * 1032 + kv0 + kt * 32 + g * 8];
            short8 vf = *(const short8*)&VtD[(w * 16 + m) * 36 + kt * 16 + g * 4];
            oacc = __builtin_amdgcn_mfma_f32_16x16x32_bf16(pf, vf, oacc, 0, 0, 0);
        }
    }

    // ---- epilogue ----
    {
        const int qrow0 = g * 4;
        const int dcol = w * 16 + m;
        ushort_t* cp = ctx + ((size_t)(b * LSEQ + q0 + qrow0)) * D_MODEL + h * DK + dcol;
        #pragma unroll
        for (int r = 0; r < 4; ++r)
            cp[(size_t)r * D_MODEL] = f2bf(oacc[r] * rowinv[qrow0 + r]);
    }
}

// ---------------------------------------------------------------------------
// LayerNorm over D=1024: x = LN(x + part2). One block per row.
// ---------------------------------------------------------------------------
__global__ __launch_bounds__(256) void ln_kernel(
    float* __restrict__ x, const float* __restrict__ part2,
    const float* __restrict__ g, const float* __restrict__ beta)
{
    const int row = blockIdx.x;
    float* xr = x + (size_t)row * D_MODEL;
    const float* pr = part2 + (size_t)row * D_MODEL;
    const int tid = threadIdx.x;

    float v[4];
    float s = 0.f, sq = 0.f;
    #pragma unroll
    for (int j = 0; j < 4; ++j) {
        v[j] = xr[tid + 256 * j] + pr[tid + 256 * j];
        s += v[j];
        sq += v[j] * v[j];
    }
    __shared__ float rs[256], rq[256];
    rs[tid] = s;
    rq[tid] = sq;
    __syncthreads();
    for (int st = 128; st > 0; st >>= 1) {
        if (tid < st) { rs[tid] += rs[tid + st]; rq[tid] += rq[tid + st]; }
        __syncthreads();
    }
    const float mean = rs[0] * (1.0f / D_MODEL);
    const float var = rq[0] * (1.0f / D_MODEL) - mean * mean;
    const float rinv = rsqrtf(var + 1e-6f);
    #pragma unroll
    for (int j = 0; j < 4; ++j) {
        int n = tid + 256 * j;
        xr[n] = (v[j] - mean) * rinv * g[n] + beta[n];
    }
}

// ---------------------------------------------------------------------------
extern "C" void kernel_launch(void* const* d_in, const int* in_sizes, int n_in,
                              void* d_out, int out_size, void* d_ws, size_t ws_size,
                              hipStream_t stream)
{
    const float* q     = (const float*)d_in[0];
    const float* k     = (const float*)d_in[1];
    const float* v     = (const float*)d_in[2];
    const float* bias  = (const float*)d_in[3];
    const float* gbias = (const float*)d_in[4];
    const float* wq    = (const float*)d_in[5];
    const float* bq    = (const float*)d_in[6];
    const float* wk    = (const float*)d_in[7];
    const float* bk    = (const float*)d_in[8];
    const float* wv    = (const float*)d_in[9];
    const float* bv    = (const float*)d_in[10];
    const float* wo    = (const float*)d_in[11];
    const float* bo    = (const float*)d_in[12];
    const float* ln_g  = (const float*)d_in[13];
    const float* ln_b  = (const float*)d_in[14];

    const size_t MB = 1u << 20;
    char* wsb = (char*)d_ws;
    ushort_t* vb   = (ushort_t*)(wsb + 0 * MB);    // 4 MB
    ushort_t* wqb  = (ushort_t*)(wsb + 4 * MB);    // 2 MB each
    ushort_t* wkb  = (ushort_t*)(wsb + 6 * MB);
    ushort_t* wvb  = (ushort_t*)(wsb + 8 * MB);
    ushort_t* wob  = (ushort_t*)(wsb + 10 * MB);
    ushort_t* qhb  = (ushort_t*)(wsb + 12 * MB);   // 4 MB each
    ushort_t* khb  = (ushort_t*)(wsb + 16 * MB);
    ushort_t* vhb  = (ushort_t*)(wsb + 20 * MB);
    ushort_t* ctxb = (ushort_t*)(wsb + 24 * MB);
    // out1 (8 MB fp32) overlays qhb+khb — both dead once attn completes.
    float* out1 = (float*)(wsb + 12 * MB);
    // d_out doubles as qb/kb scratch; dead before gemm_out writes d_out.
    ushort_t* qb = (ushort_t*)d_out;
    ushort_t* kb = (ushort_t*)d_out + (size_t)M_ROWS * D_MODEL;
    float* outp = (float*)d_out;

    const int NELEM = M_ROWS * D_MODEL;

    cast3_kernel<<<dim3(NELEM / 1024, 3), 256, 0, stream>>>(
        q, k, v, qb, kb, vb, NELEM);
    transpose4_kernel<<<dim3(32, 32, 4), 256, 0, stream>>>(
        wq, wk, wv, wo, wqb, wkb, wvb, wob);

    dim3 gqkv(D_MODEL / 64, M_ROWS / 64, 3);  // 1536 blocks
    gemm_qkv<<<gqkv, 256, 0, stream>>>(
        qb, kb, vb, wqb, wkb, wvb, bq, bk, bv, qhb, khb, vhb);

    dim3 ablk(LSEQ / 16, BATCH * N_HEADS);    // 2048 blocks
    attn_mfma<<<ablk, 256, 0, stream>>>(qhb, khb, vhb, bias, gbias, ctxb);

    dim3 gout(D_MODEL / 64, M_ROWS / 64, 2);  // 1024 blocks (split-K x2)
    gemm_out<<<gout, 256, 0, stream>>>(ctxb, wob, bo, q, outp, out1);

    ln_kernel<<<M_ROWS, 256, 0, stream>>>(outp, out1, ln_g, ln_b);
}